// Round 1
// baseline (582.502 us; speedup 1.0000x reference)
//
#include <hip/hip_runtime.h>
#include <math.h>

#define NB     65536
#define TSTEPS 100
#define DDIM   16
#define HID    64

__device__ __forceinline__ float fsigmoid(float x) {
    return 1.0f / (1.0f + __expf(-x));
}
// NaN-safe tanh: exp of a non-positive argument only.
__device__ __forceinline__ float ftanh(float x) {
    float a = fabsf(x);
    float t = __expf(-2.0f * a);
    float r = (1.0f - t) / (1.0f + t);
    return copysignf(r, x);
}

// Load X pair p (t = 2p, 2p+1; 32 floats = one 128B line per lane) into a register buffer.
#define LOADPAIR(BUF, P) do {                                              \
    _Pragma("unroll")                                                      \
    for (int q = 0; q < 8; ++q) {                                          \
        float4 v = xp[(P) * 8 + q];                                        \
        BUF[4*q+0] = v.x; BUF[4*q+1] = v.y;                                \
        BUF[4*q+2] = v.z; BUF[4*q+3] = v.w;                                \
    } } while (0)

// Two LSTM steps + fused y1 accumulation (y1[j] += relu(h_t) * W1[j][t]).
#define PROCPAIR(BUF, T0) do {                                             \
    _Pragma("unroll")                                                      \
    for (int s = 0; s < 2; ++s) {                                          \
        float g0 = fmaf(h, wh0, gb0);                                      \
        float g1 = fmaf(h, wh1, gb1);                                      \
        float g2 = fmaf(h, wh2, gb2);                                      \
        float g3 = fmaf(h, wh3, gb3);                                      \
        _Pragma("unroll")                                                  \
        for (int d = 0; d < 16; ++d) {                                     \
            float xv = BUF[s * 16 + d];                                    \
            g0 = fmaf(xv, wih[d],      g0);                                \
            g1 = fmaf(xv, wih[16 + d], g1);                                \
            g2 = fmaf(xv, wih[32 + d], g2);                                \
            g3 = fmaf(xv, wih[48 + d], g3);                                \
        }                                                                  \
        float ig = fsigmoid(g0);                                           \
        float fg = fsigmoid(g1);                                           \
        float gg = ftanh(g2);                                              \
        float og = fsigmoid(g3);                                           \
        c = fmaf(fg, c, ig * gg);                                          \
        h = og * ftanh(c);                                                 \
        float rh = fmaxf(h, 0.0f);                                         \
        const int tcur = (T0) + s;                                         \
        _Pragma("unroll")                                                  \
        for (int q = 0; q < 16; ++q) {                                     \
            float4 w = *reinterpret_cast<const float4*>(                   \
                           &sW1T[tcur * HID + 4 * q]);                     \
            y1[4*q+0] = fmaf(rh, w.x, y1[4*q+0]);                          \
            y1[4*q+1] = fmaf(rh, w.y, y1[4*q+1]);                          \
            y1[4*q+2] = fmaf(rh, w.z, y1[4*q+2]);                          \
            y1[4*q+3] = fmaf(rh, w.w, y1[4*q+3]);                          \
        }                                                                  \
    } } while (0)

__global__ void __launch_bounds__(256, 1)
lstm_mlp_fused(const float* __restrict__ X,
               const float* __restrict__ W_ih,
               const float* __restrict__ W_hh,
               const float* __restrict__ b_ih,
               const float* __restrict__ b_hh,
               const float* __restrict__ W1,
               const float* __restrict__ b1,
               const float* __restrict__ W2,
               const float* __restrict__ b2,
               const float* __restrict__ W3,
               const float* __restrict__ b3,
               float* __restrict__ out)
{
    // All weights LDS-resident (~43 KB); W1 stored transposed so the scan reads
    // a contiguous 64-float row per t (broadcast ds_read_b128, conflict-free).
    __shared__ __align__(16) float sW1T[TSTEPS * HID];
    __shared__ __align__(16) float sW2[HID * HID];
    __shared__ __align__(16) float sW3[2 * HID];
    __shared__ __align__(16) float sB1[HID];
    __shared__ __align__(16) float sB2[HID];
    __shared__ __align__(16) float sWih[4 * DDIM];
    __shared__ float sMisc[12];   // [0:4) b_ih+b_hh, [4:8) W_hh, [8:10) b3

    const int tid = threadIdx.x;
    for (int i = tid; i < TSTEPS * HID; i += 256) {
        int j = i / TSTEPS;           // W1 is (HID, T) row-major
        int t = i - j * TSTEPS;
        sW1T[t * HID + j] = W1[i];
    }
    for (int i = tid; i < HID * HID; i += 256) sW2[i] = W2[i];
    if (tid < 2 * HID) sW3[tid] = W3[tid];
    if (tid < HID) { sB1[tid] = b1[tid]; sB2[tid] = b2[tid]; }
    if (tid < 4 * DDIM) sWih[tid] = W_ih[tid];
    if (tid < 4) { sMisc[tid] = b_ih[tid] + b_hh[tid]; sMisc[4 + tid] = W_hh[tid]; }
    if (tid < 2) sMisc[8 + tid] = b3[tid];
    __syncthreads();

    // Per-thread register copies of the tiny uniform weights (budget: ~1 wave/SIMD
    // grid-limited occupancy -> ~512 VGPRs available, we use ~220).
    float wih[64];
    #pragma unroll
    for (int q = 0; q < 16; ++q) {
        float4 v = *reinterpret_cast<const float4*>(&sWih[4 * q]);
        wih[4*q+0] = v.x; wih[4*q+1] = v.y; wih[4*q+2] = v.z; wih[4*q+3] = v.w;
    }
    const float gb0 = sMisc[0], gb1 = sMisc[1], gb2 = sMisc[2], gb3 = sMisc[3];
    const float wh0 = sMisc[4], wh1 = sMisc[5], wh2 = sMisc[6], wh3 = sMisc[7];
    const float bo0 = sMisc[8], bo1 = sMisc[9];

    const int b = blockIdx.x * 256 + tid;
    const float4* __restrict__ xp =
        reinterpret_cast<const float4*>(X + (size_t)b * (TSTEPS * DDIM));

    float y1[HID];
    #pragma unroll
    for (int q = 0; q < 16; ++q) {
        float4 v = *reinterpret_cast<const float4*>(&sB1[4 * q]);
        y1[4*q+0] = v.x; y1[4*q+1] = v.y; y1[4*q+2] = v.z; y1[4*q+3] = v.w;
    }

    float h = 0.0f, c = 0.0f;
    float bufA[32], bufB[32];

    // Software pipeline: always one 128B/lane pair in flight while computing the
    // previous one (keeps >9KB/CU outstanding -> HBM BW saturates at 4 waves/CU).
    LOADPAIR(bufA, 0);
    for (int it = 0; it < 25; ++it) {
        LOADPAIR(bufB, 2 * it + 1);
        PROCPAIR(bufA, 4 * it);
        if (it < 24) LOADPAIR(bufA, 2 * it + 2);
        PROCPAIR(bufB, 4 * it + 2);
    }

    // MLP tail. y1 -> relu in place; layer 3 accumulated incrementally (no y2 array).
    #pragma unroll
    for (int j = 0; j < HID; ++j) y1[j] = fmaxf(y1[j], 0.0f);

    float o0 = bo0, o1 = bo1;
    for (int k = 0; k < HID; ++k) {       // rolled: keeps code size small
        float acc = sB2[k];
        #pragma unroll
        for (int q = 0; q < 16; ++q) {
            float4 w = *reinterpret_cast<const float4*>(&sW2[k * HID + 4 * q]);
            acc = fmaf(y1[4*q+0], w.x, acc);
            acc = fmaf(y1[4*q+1], w.y, acc);
            acc = fmaf(y1[4*q+2], w.z, acc);
            acc = fmaf(y1[4*q+3], w.w, acc);
        }
        acc = fmaxf(acc, 0.0f);
        o0 = fmaf(acc, sW3[k], o0);
        o1 = fmaf(acc, sW3[HID + k], o1);
    }

    // log_softmax over the 2 logits
    float m = fmaxf(o0, o1);
    float lse = m + __logf(__expf(o0 - m) + __expf(o1 - m));
    float2 res = make_float2(o0 - lse, o1 - lse);
    reinterpret_cast<float2*>(out)[b] = res;
}

extern "C" void kernel_launch(void* const* d_in, const int* in_sizes, int n_in,
                              void* d_out, int out_size, void* d_ws, size_t ws_size,
                              hipStream_t stream) {
    const float* X    = (const float*)d_in[0];
    const float* W_ih = (const float*)d_in[1];
    const float* W_hh = (const float*)d_in[2];
    const float* b_ih = (const float*)d_in[3];
    const float* b_hh = (const float*)d_in[4];
    const float* W1   = (const float*)d_in[5];
    const float* b1   = (const float*)d_in[6];
    const float* W2   = (const float*)d_in[7];
    const float* b2   = (const float*)d_in[8];
    const float* W3   = (const float*)d_in[9];
    const float* b3   = (const float*)d_in[10];
    float* out = (float*)d_out;

    lstm_mlp_fused<<<NB / 256, 256, 0, stream>>>(
        X, W_ih, W_hh, b_ih, b_hh, W1, b1, W2, b2, W3, b3, out);
}